// Round 2
// baseline (723.983 us; speedup 1.0000x reference)
//
#include <hip/hip_runtime.h>
#include <hip/hip_bf16.h>
#include <stdint.h>

// Problem constants
#define NATOMS 32768
#define DDIM   1024
#define HDIM   1024
#define ENUM   4
// Expert segments padded to 256 so a 256-row GEMM tile never spans two experts.
// Worst-case padded M <= 33536; cap 33792 (132*256) for slack.
#define MCAP   33792
#define MT256  132

typedef unsigned short u16;
typedef unsigned char  u8;
typedef __attribute__((ext_vector_type(8)))  int   i32x8;
typedef __attribute__((ext_vector_type(16))) float f32x16;

// ---- workspace layout (bytes) ----
static const size_t XP_OFF   = 0;
static const size_t H1_OFF   = XP_OFF  + (size_t)MCAP * 1024;
static const size_t W1T_OFF  = H1_OFF  + (size_t)MCAP * 1024;
static const size_t W2T_OFF  = W1T_OFF + (size_t)ENUM * 1024 * 1024;
static const size_t PERM_OFF = W2T_OFF + (size_t)ENUM * 1024 * 1024;
static const size_t META_OFF = PERM_OFF + (size_t)MCAP * 4;
// meta ints: count[e] at e*16; cursor[e] at 64+e*16; offs[0..3] at 128..131;
// Mpad at 132; per-block count partials at 256 + b*4 + e  (b in [0,128))

__device__ __forceinline__ u8 f2fp8(float x) {
    int w = __builtin_amdgcn_cvt_pk_fp8_f32(x, x, 0, false);
    return (u8)(w & 0xFF);
}

// ------- count atoms per expert: per-block partials, no pre-zeroed meta -------
__global__ void k_count(const int* __restrict__ sym, int* __restrict__ meta) {
    __shared__ int cnt[4];
    int t = threadIdx.x;
    if (t < 4) cnt[t] = 0;
    __syncthreads();
    int n = blockIdx.x * 256 + t;
    int lane = t & 63;
    int e = sym[n];
#pragma unroll
    for (int j = 0; j < ENUM; ++j) {
        unsigned long long mask = __ballot(e == j);
        if (mask) {
            int leader = __ffsll((long long)mask) - 1;
            if (lane == leader) atomicAdd(&cnt[j], __popcll(mask));
        }
    }
    __syncthreads();
    if (t < 4) meta[256 + blockIdx.x * 4 + t] = cnt[t];
}

// -- sum partials; write counts/cursors/offs/Mpad; out = constant energy term --
__global__ void k_offsets(int* __restrict__ meta, const float* __restrict__ slope,
                          const float* __restrict__ b3, const float* __restrict__ inter,
                          float* __restrict__ out) {
    __shared__ int tot[4];
    int t = threadIdx.x;
    if (t < 4) {
        int s = 0;
#pragma unroll 8
        for (int b = 0; b < 128; ++b) s += meta[256 + b * 4 + t];
        tot[t] = s;
    }
    __syncthreads();
    if (t == 0) {
        int off = 0;
        float c = 0.f;
        for (int e = 0; e < 4; ++e) {
            int cnt = tot[e];
            meta[e * 16]     = cnt;   // total count
            meta[128 + e]    = off;   // segment start
            meta[64 + e*16]  = off;   // scatter cursor
            c += (float)cnt * (slope[e] * b3[e] + inter[e]);
            off += (cnt + 255) & ~255;   // pad to 256 for 256-row tiles
        }
        meta[132] = off;              // Mpad
        out[0] = c;                   // per-atom constant terms, summed
    }
}

// ---------------- scatter atom ids (wave-aggregated: 4 atomics/wave) ----------------
__global__ void k_scatter(const int* __restrict__ sym, int* __restrict__ meta,
                          int* __restrict__ perm) {
    int n = blockIdx.x * 256 + threadIdx.x;
    int lane = threadIdx.x & 63;
    int e = sym[n];
#pragma unroll
    for (int j = 0; j < ENUM; ++j) {
        unsigned long long mask = __ballot(e == j);
        if (mask) {
            int leader = __ffsll((long long)mask) - 1;
            int base = 0;
            if (lane == leader)
                base = atomicAdd(&meta[64 + j * 16], __popcll(mask));
            base = __shfl(base, leader, 64);
            if (e == j) {
                int rank = __popcll(mask & ((1ull << lane) - 1ull));
                perm[base + rank] = n;
            }
        }
    }
}

// -------- features fp32 -> permuted fp8 (pad slots -> zeros, via offs/count) --------
__global__ void k_convx(const float* __restrict__ F, const int* __restrict__ perm,
                        const int* __restrict__ meta, u8* __restrict__ Xp) {
    int g = blockIdx.x * 256 + threadIdx.x;    // chunk of 8 elements
    int slot = g >> 7, c = g & 127;
    const int* offs = meta + 128;
    int e = (slot >= offs[1]) + (slot >= offs[2]) + (slot >= offs[3]);
    bool valid = slot < offs[e] + meta[e * 16];
    uint2 v;
    if (!valid) {
        v.x = 0u; v.y = 0u;
    } else {
        int src = perm[slot];
        const float* fp = F + (size_t)src * 1024 + c * 8;
        int w0 = 0, w1 = 0;
        w0 = __builtin_amdgcn_cvt_pk_fp8_f32(fp[0], fp[1], w0, false);
        w0 = __builtin_amdgcn_cvt_pk_fp8_f32(fp[2], fp[3], w0, true);
        w1 = __builtin_amdgcn_cvt_pk_fp8_f32(fp[4], fp[5], w1, false);
        w1 = __builtin_amdgcn_cvt_pk_fp8_f32(fp[6], fp[7], w1, true);
        v.x = (unsigned)w0; v.y = (unsigned)w1;
    }
    *(uint2*)(void*)(Xp + (size_t)g * 8) = v;
}

// -------- W [E][K][N] fp32 -> WT [E][N][K] fp8 of 32*W (z: 0=W1,1=W2) --------
__global__ void k_transw(const float* __restrict__ W1, u8* __restrict__ W1T,
                         const float* __restrict__ W2, u8* __restrict__ W2T) {
    __shared__ u8 tile[64][65];
    const float* W  = blockIdx.z ? W2  : W1;
    u8*          WT = blockIdx.z ? W2T : W1T;
    int e  = blockIdx.y;
    int tn = blockIdx.x & 15;
    int tk = blockIdx.x >> 4;
    const float* Wp = W  + (size_t)e * 1024 * 1024;
    u8*         WTp = WT + (size_t)e * 1024 * 1024;
    int c = threadIdx.x & 63, r0 = threadIdx.x >> 6;
#pragma unroll
    for (int i = 0; i < 16; ++i) {
        int r = r0 + i * 4;
        tile[r][c] = f2fp8(32.0f * Wp[(size_t)(tk * 64 + r) * 1024 + tn * 64 + c]);
    }
    __syncthreads();
#pragma unroll
    for (int i = 0; i < 16; ++i) {
        int r = r0 + i * 4;
        WTp[(size_t)(tn * 64 + r) * 1024 + tk * 64 + c] = tile[c][r];
    }
}

// ---------------- MX-fp8 MFMA GEMM: relu(A * (32B)^T * 2^-5 + bias) ----------------
// R10: 256x256 tile, BK=128, 8 waves (2Mx4N, 128x64/wave), double-buffered
// 128 KiB LDS, PER-PHASE interleave (T3): 4 phases per K-tile, each
//   {stage 1 pair of tile t+1 | ds_read this phase's frags | s_barrier |
//    setprio(1) + 4 MFMA + setprio(0) | s_barrier}
// with COUNTED vmcnt(2) only at phase 0 (T4; never 0 in-loop) and T5 setprio.
// R9 post-mortem: same tile on a COARSE 2-barrier loop regressed (377 vs 349) --
// matches learn_hip m230/m233 (2-phase at 256^2 is stage+wait-bound; T4/T5 null
// without phase interleave). This is the m201 8-phase schedule adapted to fp8
// 32x32x64 (16 MFMA/K-tile split 4x4, stage split 4 pairs).
// Race-freedom: phase-0 vmcnt(2)+barrier => tile t fully in LDS for all waves
// before any phase reads it; post-MFMA barrier per phase => no wave can issue
// tile t+2 stage (into buf[cur]) until all waves' phase-3 ds_reads COMPLETED
// (MFMA issue requires lgkm-waited operands).
// LDS swizzle (unchanged): 16B chunk c of row r holds global chunk c^(r&7).
// XCD swizzle: 528 blocks = 66*8 chunked bijective; nt fastest per XCD.
template <bool FUSE>
__global__ __launch_bounds__(512, 2)
void k_gemm(const u8* __restrict__ A, const u8* __restrict__ BT,
            const float* __restrict__ bias, u8* __restrict__ C,
            const int* __restrict__ meta, const float* __restrict__ W3,
            const float* __restrict__ slope, float* __restrict__ out) {
    __shared__ u8 As[2][32768];
    __shared__ u8 Bs[2][32768];
    const int* offs = meta + 128;

    // grid = dim3(8, 66) -> flat 0..527; XCD = flat&7 gets contiguous wgid chunk
    const int flat = blockIdx.y * 8 + blockIdx.x;
    const int wgid = (flat & 7) * 66 + (flat >> 3);
    const int mt = wgid >> 2;                  // m tile (0..131)
    const int nt = wgid & 3;                   // n tile (0..3), fast index
    const int m0 = mt * 256, n0 = nt * 256;
    if (m0 >= meta[132]) return;               // beyond actual padded M
    const int e = (m0 >= offs[1]) + (m0 >= offs[2]) + (m0 >= offs[3]);

    const int t = threadIdx.x;                 // 0..511
    const int w = t >> 6, lane = t & 63;
    const int l31 = lane & 31, khalf = lane >> 5;
    const int wm = w & 1, wn = w >> 1;         // 2x4 waves, each 128x64

    const u8* Ag = A  + (size_t)m0 * 1024;
    const u8* Bg = BT + (size_t)e * 1024 * 1024 + (size_t)n0 * 1024;

    // staging: pair i covers rows i*64+(t>>3) of A and B, 16B chunk t&7,
    // swizzled source chunk (t&7)^(row&7); LDS linear (global_load_lds rule).
    const int srow = t >> 3;                   // 0..63
    const int gcol = ((t & 7) ^ (srow & 7)) * 16;

    f32x16 acc[4][2] = {};

#define SPAIR(buf, ktile, i)                                                    \
    do {                                                                        \
        const size_t kb = (size_t)(ktile) * 128;                                \
        __builtin_amdgcn_global_load_lds(                                       \
            (const void*)(Ag + (size_t)((i) * 64 + srow) * 1024 + kb + gcol),   \
            (void*)(&As[buf][(i) * 8192 + w * 1024]), 16, 0, 0);                \
        __builtin_amdgcn_global_load_lds(                                       \
            (const void*)(Bg + (size_t)((i) * 64 + srow) * 1024 + kb + gcol),   \
            (void*)(&Bs[buf][(i) * 8192 + w * 1024]), 16, 0, 0);                \
    } while (0)

    // fragment read: 2x ds_read_b128 with XOR-chunk deswizzle
#define FRAG(dst, basep, rowsel, c0)                                            \
    do {                                                                        \
        int lo_ = (((c0) ^ ((rowsel) & 7)) << 4);                               \
        union { uint4 q[2]; i32x8 v; } u_;                                      \
        u_.q[0] = *(const uint4*)(const void*)((basep) + lo_);                  \
        u_.q[1] = *(const uint4*)(const void*)((basep) + (lo_ ^ 16));           \
        dst = u_.v;                                                             \
    } while (0)

#define MFMA4(mi, av)                                                           \
    do {                                                                        \
        __builtin_amdgcn_s_setprio(1);                                          \
        _Pragma("unroll")                                                       \
        for (int ni_ = 0; ni_ < 2; ++ni_)                                       \
            _Pragma("unroll")                                                   \
            for (int ks_ = 0; ks_ < 2; ++ks_)                                   \
                acc[mi][ni_] = __builtin_amdgcn_mfma_scale_f32_32x32x64_f8f6f4( \
                    (av)[ks_], b[ni_][ks_], acc[mi][ni_],                       \
                    0, 0,                      /* fp8 e4m3 A and B */           \
                    0, 0x7F7F7F7F,             /* A scale 2^0     */            \
                    0, 0x7A7A7A7A);            /* B scale 2^-5    */            \
        __builtin_amdgcn_s_setprio(0);                                          \
    } while (0)

#define FENCE asm volatile("" ::: "memory")
#define BAR   do { FENCE; __builtin_amdgcn_s_barrier(); FENCE; } while (0)

    // prologue: all 4 pairs of tile 0 -> buf 0 (8 loads outstanding)
#pragma unroll
    for (int i = 0; i < 4; ++i) SPAIR(0, 0, i);

#pragma unroll 2
    for (int kt = 0; kt < 8; ++kt) {
        const int cur = kt & 1;
        const u8* Ab = &As[cur][0];
        const u8* Bb = &Bs[cur][0];

        // ---- phase 0: vmcnt + sync, read all B frags + A0, MFMA mi=0 ----
        if (kt < 7) {
            SPAIR(cur ^ 1, kt + 1, 0);
            asm volatile("s_waitcnt vmcnt(2)" ::: "memory");  // tile kt landed
        } else {
            asm volatile("s_waitcnt vmcnt(0)" ::: "memory");
        }
        BAR;                                   // tile kt visible to all waves

        i32x8 b[2][2];
#pragma unroll
        for (int ni = 0; ni < 2; ++ni)
#pragma unroll
            for (int ks = 0; ks < 2; ++ks) {
                int n = wn * 64 + ni * 32 + l31;
                FRAG(b[ni][ks], Bb + n * 128, n, 4 * ks + 2 * khalf);
            }
        {
            i32x8 a0[2];
            int m = wm * 128 + 0 * 32 + l31;
#pragma unroll
            for (int ks = 0; ks < 2; ++ks)
                FRAG(a0[ks], Ab + m * 128, m, 4 * ks + 2 * khalf);
            MFMA4(0, a0);
        }
        BAR;                                   // close phase 0

        // ---- phases 1..3: read A_mi + stage pair mi, barrier, MFMA mi ----
#pragma unroll
        for (int mi = 1; mi < 4; ++mi) {
            i32x8 am[2];
            int m = wm * 128 + mi * 32 + l31;
#pragma unroll
            for (int ks = 0; ks < 2; ++ks)
                FRAG(am[ks], Ab + m * 128, m, 4 * ks + 2 * khalf);
            if (kt < 7) SPAIR(cur ^ 1, kt + 1, mi);
            BAR;                               // align waves: reads vs MFMAs
            MFMA4(mi, am);
            BAR;                               // close phase (drains ds_reads
        }                                      //  before anyone can re-stage)
    }
#undef SPAIR
#undef FRAG
#undef MFMA4
#undef FENCE
#undef BAR

    // epilogue.  32x32 C/D layout: col=lane&31, row=(reg&3)+8*(reg>>2)+4*(lane>>5)
    if (!FUSE) {
#pragma unroll
        for (int ni = 0; ni < 2; ++ni) {
            int col = n0 + wn * 64 + ni * 32 + l31;
            float bv = bias[e * 1024 + col];
#pragma unroll
            for (int mi = 0; mi < 4; ++mi) {
                int rowb = m0 + wm * 128 + mi * 32 + 4 * khalf;
#pragma unroll
                for (int reg = 0; reg < 16; ++reg) {
                    int rowg = rowb + (reg & 3) + 8 * (reg >> 2);
                    float v = acc[mi][ni][reg] + bv;
                    v = v > 0.f ? v : 0.f;
                    C[(size_t)rowg * 1024 + col] = f2fp8(v);
                }
            }
        }
    } else {
        const int segEnd = offs[e] + meta[e * 16];   // valid slots < segEnd
        const float se = slope[e];
        float psum = 0.f;
#pragma unroll
        for (int ni = 0; ni < 2; ++ni) {
            int col = n0 + wn * 64 + ni * 32 + l31;
            float bv  = bias[e * 1024 + col];
            float w3s = W3[e * 1024 + col] * se;
#pragma unroll
            for (int mi = 0; mi < 4; ++mi) {
                int rowb = m0 + wm * 128 + mi * 32 + 4 * khalf;
#pragma unroll
                for (int reg = 0; reg < 16; ++reg) {
                    int rowg = rowb + (reg & 3) + 8 * (reg >> 2);
                    float v = acc[mi][ni][reg] + bv;
                    v = v > 0.f ? v : 0.f;
                    psum += (rowg < segEnd) ? v * w3s : 0.f;
                }
            }
        }
#pragma unroll
        for (int o = 32; o; o >>= 1) psum += __shfl_xor(psum, o, 64);
        __syncthreads();                     // all waves done with LDS reads
        float* red = (float*)As;
        if (lane == 0) red[w] = psum;
        __syncthreads();
        if (t == 0) {
            float s = 0.f;
#pragma unroll
            for (int i = 0; i < 8; ++i) s += red[i];
            atomicAdd(out, s);
        }
    }
}

extern "C" void kernel_launch(void* const* d_in, const int* in_sizes, int n_in,
                              void* d_out, int out_size, void* d_ws, size_t ws_size,
                              hipStream_t stream) {
    const float* features = (const float*)d_in[0];
    const int*   sym      = (const int*)d_in[1];
    const float* W1       = (const float*)d_in[2];
    const float* b1       = (const float*)d_in[3];
    const float* W2       = (const float*)d_in[4];
    const float* b2       = (const float*)d_in[5];
    const float* W3       = (const float*)d_in[6];
    const float* b3       = (const float*)d_in[7];
    const float* slope    = (const float*)d_in[8];
    const float* inter    = (const float*)d_in[9];
    float* out = (float*)d_out;

    char* ws  = (char*)d_ws;
    u8*  Xp   = (u8*)(ws + XP_OFF);
    u8*  H1b  = (u8*)(ws + H1_OFF);
    u8*  W1T  = (u8*)(ws + W1T_OFF);
    u8*  W2T  = (u8*)(ws + W2T_OFF);
    int* perm = (int*)(ws + PERM_OFF);
    int* meta = (int*)(ws + META_OFF);

    k_count<<<NATOMS / 256, 256, 0, stream>>>(sym, meta);
    k_offsets<<<1, 256, 0, stream>>>(meta, slope, b3, inter, out);
    k_scatter<<<NATOMS / 256, 256, 0, stream>>>(sym, meta, perm);
    k_convx<<<(MCAP * 128) / 256, 256, 0, stream>>>(features, perm, meta, Xp);
    k_transw<<<dim3(256, 4, 2), 256, 0, stream>>>(W1, W1T, W2, W2T);
    k_gemm<false><<<dim3(8, 66), 512, 0, stream>>>(Xp, W1T, b1, H1b, meta,
                                                   nullptr, nullptr, nullptr);
    k_gemm<true><<<dim3(8, 66), 512, 0, stream>>>(H1b, W2T, b2, nullptr, meta,
                                                  W3, slope, out);
}

// Round 3
// 347.400 us; speedup vs baseline: 2.0840x; 2.0840x over previous
//
#include <hip/hip_runtime.h>
#include <hip/hip_bf16.h>
#include <stdint.h>

// Problem constants
#define NATOMS 32768
#define DDIM   1024
#define HDIM   1024
#define ENUM   4
// Expert segments padded to 256 so a 256-row GEMM tile never spans two experts.
// Worst-case padded M <= 33536; cap 33792 (132*256) for slack.
#define MCAP   33792

typedef unsigned short u16;
typedef unsigned char  u8;
typedef __attribute__((ext_vector_type(8)))  int   i32x8;
typedef __attribute__((ext_vector_type(16))) float f32x16;

// ---- workspace layout (bytes) ----
static const size_t XP_OFF   = 0;
static const size_t H1_OFF   = XP_OFF  + (size_t)MCAP * 1024;
static const size_t W1T_OFF  = H1_OFF  + (size_t)MCAP * 1024;
static const size_t W2T_OFF  = W1T_OFF + (size_t)ENUM * 1024 * 1024;
static const size_t PERM_OFF = W2T_OFF + (size_t)ENUM * 1024 * 1024;
static const size_t META_OFF = PERM_OFF + (size_t)MCAP * 4;
// meta ints: count[e] at e*16; cursor[e] at 64+e*16; offs[0..3] at 128..131;
// Mpad at 132; per-block count partials at 256 + b*4 + e  (b in [0,128))

__device__ __forceinline__ u8 f2fp8(float x) {
    int w = __builtin_amdgcn_cvt_pk_fp8_f32(x, x, 0, false);
    return (u8)(w & 0xFF);
}

// ------- count atoms per expert: per-block partials, no pre-zeroed meta -------
__global__ void k_count(const int* __restrict__ sym, int* __restrict__ meta) {
    __shared__ int cnt[4];
    int t = threadIdx.x;
    if (t < 4) cnt[t] = 0;
    __syncthreads();
    int n = blockIdx.x * 256 + t;
    int lane = t & 63;
    int e = sym[n];
#pragma unroll
    for (int j = 0; j < ENUM; ++j) {
        unsigned long long mask = __ballot(e == j);
        if (mask) {
            int leader = __ffsll((long long)mask) - 1;
            if (lane == leader) atomicAdd(&cnt[j], __popcll(mask));
        }
    }
    __syncthreads();
    if (t < 4) meta[256 + blockIdx.x * 4 + t] = cnt[t];
}

// -- sum partials; write counts/cursors/offs/Mpad; out = constant energy term --
__global__ void k_offsets(int* __restrict__ meta, const float* __restrict__ slope,
                          const float* __restrict__ b3, const float* __restrict__ inter,
                          float* __restrict__ out) {
    __shared__ int tot[4];
    int t = threadIdx.x;
    if (t < 4) {
        int s = 0;
#pragma unroll 8
        for (int b = 0; b < 128; ++b) s += meta[256 + b * 4 + t];
        tot[t] = s;
    }
    __syncthreads();
    if (t == 0) {
        int off = 0;
        float c = 0.f;
        for (int e = 0; e < 4; ++e) {
            int cnt = tot[e];
            meta[e * 16]     = cnt;   // total count
            meta[128 + e]    = off;   // segment start
            meta[64 + e*16]  = off;   // scatter cursor
            c += (float)cnt * (slope[e] * b3[e] + inter[e]);
            off += (cnt + 255) & ~255;   // pad to 256 for 256-row tiles
        }
        meta[132] = off;              // Mpad
        out[0] = c;                   // per-atom constant terms, summed
    }
}

// ---------------- scatter atom ids (wave-aggregated: 4 atomics/wave) ----------------
__global__ void k_scatter(const int* __restrict__ sym, int* __restrict__ meta,
                          int* __restrict__ perm) {
    int n = blockIdx.x * 256 + threadIdx.x;
    int lane = threadIdx.x & 63;
    int e = sym[n];
#pragma unroll
    for (int j = 0; j < ENUM; ++j) {
        unsigned long long mask = __ballot(e == j);
        if (mask) {
            int leader = __ffsll((long long)mask) - 1;
            int base = 0;
            if (lane == leader)
                base = atomicAdd(&meta[64 + j * 16], __popcll(mask));
            base = __shfl(base, leader, 64);
            if (e == j) {
                int rank = __popcll(mask & ((1ull << lane) - 1ull));
                perm[base + rank] = n;
            }
        }
    }
}

// -------- features fp32 -> permuted fp8 (pad slots -> zeros, via offs/count) --------
__global__ void k_convx(const float* __restrict__ F, const int* __restrict__ perm,
                        const int* __restrict__ meta, u8* __restrict__ Xp) {
    int g = blockIdx.x * 256 + threadIdx.x;    // chunk of 8 elements
    int slot = g >> 7, c = g & 127;
    const int* offs = meta + 128;
    int e = (slot >= offs[1]) + (slot >= offs[2]) + (slot >= offs[3]);
    bool valid = slot < offs[e] + meta[e * 16];
    uint2 v;
    if (!valid) {
        v.x = 0u; v.y = 0u;
    } else {
        int src = perm[slot];
        const float* fp = F + (size_t)src * 1024 + c * 8;
        int w0 = 0, w1 = 0;
        w0 = __builtin_amdgcn_cvt_pk_fp8_f32(fp[0], fp[1], w0, false);
        w0 = __builtin_amdgcn_cvt_pk_fp8_f32(fp[2], fp[3], w0, true);
        w1 = __builtin_amdgcn_cvt_pk_fp8_f32(fp[4], fp[5], w1, false);
        w1 = __builtin_amdgcn_cvt_pk_fp8_f32(fp[6], fp[7], w1, true);
        v.x = (unsigned)w0; v.y = (unsigned)w1;
    }
    *(uint2*)(void*)(Xp + (size_t)g * 8) = v;
}

// -------- W [E][K][N] fp32 -> WT [E][N][K] fp8 of 32*W (z: 0=W1,1=W2) --------
__global__ void k_transw(const float* __restrict__ W1, u8* __restrict__ W1T,
                         const float* __restrict__ W2, u8* __restrict__ W2T) {
    __shared__ u8 tile[64][65];
    const float* W  = blockIdx.z ? W2  : W1;
    u8*          WT = blockIdx.z ? W2T : W1T;
    int e  = blockIdx.y;
    int tn = blockIdx.x & 15;
    int tk = blockIdx.x >> 4;
    const float* Wp = W  + (size_t)e * 1024 * 1024;
    u8*         WTp = WT + (size_t)e * 1024 * 1024;
    int c = threadIdx.x & 63, r0 = threadIdx.x >> 6;
#pragma unroll
    for (int i = 0; i < 16; ++i) {
        int r = r0 + i * 4;
        tile[r][c] = f2fp8(32.0f * Wp[(size_t)(tk * 64 + r) * 1024 + tn * 64 + c]);
    }
    __syncthreads();
#pragma unroll
    for (int i = 0; i < 16; ++i) {
        int r = r0 + i * 4;
        WTp[(size_t)(tn * 64 + r) * 1024 + tk * 64 + c] = tile[c][r];
    }
}

// ---------------- MX-fp8 MFMA GEMM: relu(A * (32B)^T * 2^-5 + bias) ----------------
// R11: back to the PROVEN R7 skeleton (single-buffered LDS, __syncthreads
// 2-barrier K-loop, multi-block/CU implicit overlap -- m114), with ONE change:
// 256x128 block tile, 4 waves of 128x64 each (was 128x128 / 64x64 waves).
// Why: R7 was LDS-read-bound, not MFMA-bound. Per CU per K-tile, R7 spent
// 3072 cy on ds_read_b128 (2.0 reads/MFMA) vs 2202 cy of MFMA. 128x64 wave
// tiles cut fragment reads to 1.5/MFMA -> LDS 2304 cy ~= MFMA 2202 cy.
// acc[4][2] = 128 regs lives in the AGPR half; __launch_bounds__(256,2)
// gives the 256-reg budget. LDS 48 KB -> 2 blocks/CU (cross-block overlap
// across the barrier drain, which R9/R10's 1-block/CU 256^2 ports lost).
// R10 post-mortem: per-phase raw-barrier port spilled catastrophically
// (WRITE_SIZE 487 MB of scratch on a kernel with ~0 logical writes,
// MfmaUtil 5.5%). 8-phase template abandoned; no raw barriers here.
// LDS swizzle (unchanged): 16B chunk c of row r holds global chunk c^(r&7).
// XCD swizzle: grid dim3(8,132) -> 1056 = 132*8 chunked bijective; nt fastest
// per XCD so the 8 blocks sharing an A-panel (256 KB, L2-fits) are co-XCD.
// FUSE=false: store fp8 C.  FUSE=true: fold layer3 dot + slope + global sum.
template <bool FUSE>
__global__ __launch_bounds__(256, 2)
void k_gemm(const u8* __restrict__ A, const u8* __restrict__ BT,
            const float* __restrict__ bias, u8* __restrict__ C,
            const int* __restrict__ meta, const float* __restrict__ W3,
            const float* __restrict__ slope, float* __restrict__ out) {
    __shared__ u8 As[256 * 128];   // 32 KB
    __shared__ u8 Bs[128 * 128];   // 16 KB
    const int* offs = meta + 128;

    // grid = dim3(8, 132) -> flat 0..1055; XCD = flat&7 gets contiguous chunk
    const int flat = blockIdx.y * 8 + blockIdx.x;
    const int wgid = (flat & 7) * 132 + (flat >> 3);
    const int mt = wgid >> 3;                  // m tile (0..131), 256 rows
    const int nt = wgid & 7;                   // n tile (0..7), fast index
    const int m0 = mt * 256, n0 = nt * 128;
    if (m0 >= meta[132]) return;               // beyond actual padded M
    const int e = (m0 >= offs[1]) + (m0 >= offs[2]) + (m0 >= offs[3]);

    const int t = threadIdx.x;                 // 0..255
    const int w = t >> 6, lane = t & 63;
    const int l31 = lane & 31, khalf = lane >> 5;
    const int wm = w & 1, wn = w >> 1;         // 2x2 waves, each 128x64

    const u8* Ag = A  + (size_t)m0 * 1024;
    const u8* Bg = BT + (size_t)e * 1024 * 1024 + (size_t)n0 * 1024;

    // staging: instr i covers rows i*32+(t>>3), 16B chunk t&7, swizzled
    // source chunk (t&7)^(row&7); LDS linear (global_load_lds rule).
    const int srow   = t >> 3;                 // 0..31
    const int gcol   = ((t & 7) ^ (srow & 7)) * 16;

    f32x16 acc[4][2] = {};

    for (int kt = 0; kt < 1024 / 128; ++kt) {
        const int kb = kt * 128;
#pragma unroll
        for (int i = 0; i < 8; ++i) {          // A: 256 rows, 8 instrs
            __builtin_amdgcn_global_load_lds(
                (const void*)(Ag + (size_t)(i * 32 + srow) * 1024 + kb + gcol),
                (void*)(As + i * 4096 + w * 1024), 16, 0, 0);
        }
#pragma unroll
        for (int i = 0; i < 4; ++i) {          // B: 128 rows, 4 instrs
            __builtin_amdgcn_global_load_lds(
                (const void*)(Bg + (size_t)(i * 32 + srow) * 1024 + kb + gcol),
                (void*)(Bs + i * 4096 + w * 1024), 16, 0, 0);
        }
        __syncthreads();

#pragma unroll
        for (int kk = 0; kk < 2; ++kk) {
            const int c0 = 4 * kk + 2 * khalf;    // even
            i32x8 b[2];
#pragma unroll
            for (int ni = 0; ni < 2; ++ni) {
                int n = wn * 64 + ni * 32 + l31;
                const u8* base = Bs + n * 128;
                int lo = ((c0 ^ (n & 7)) << 4);
                union { uint4 q[2]; i32x8 v; } u;
                u.q[0] = *(const uint4*)(const void*)(base + lo);
                u.q[1] = *(const uint4*)(const void*)(base + (lo ^ 16));
                b[ni] = u.v;
            }
#pragma unroll
            for (int mi = 0; mi < 4; ++mi) {
                int m = wm * 128 + mi * 32 + l31;
                const u8* base = As + m * 128;
                int lo = ((c0 ^ (m & 7)) << 4);
                union { uint4 q[2]; i32x8 v; } u;
                u.q[0] = *(const uint4*)(const void*)(base + lo);
                u.q[1] = *(const uint4*)(const void*)(base + (lo ^ 16));
                i32x8 a = u.v;
#pragma unroll
                for (int ni = 0; ni < 2; ++ni)
                    acc[mi][ni] = __builtin_amdgcn_mfma_scale_f32_32x32x64_f8f6f4(
                        a, b[ni], acc[mi][ni],
                        0, 0,                       // cbsz=fp8(e4m3), blgp=fp8(e4m3)
                        0, 0x7F7F7F7F,              // A scale 2^0
                        0, 0x7A7A7A7A);             // B scale 2^-5 (undo 32*W)
            }
        }
        __syncthreads();
    }

    // epilogue.  32x32 C/D layout: col=lane&31, row=(reg&3)+8*(reg>>2)+4*(lane>>5)
    if (!FUSE) {
#pragma unroll
        for (int ni = 0; ni < 2; ++ni) {
            int col = n0 + wn * 64 + ni * 32 + l31;
            float bv = bias[e * 1024 + col];
#pragma unroll
            for (int mi = 0; mi < 4; ++mi) {
                int rowb = m0 + wm * 128 + mi * 32 + 4 * khalf;
#pragma unroll
                for (int reg = 0; reg < 16; ++reg) {
                    int rowg = rowb + (reg & 3) + 8 * (reg >> 2);
                    float v = acc[mi][ni][reg] + bv;
                    v = v > 0.f ? v : 0.f;
                    C[(size_t)rowg * 1024 + col] = f2fp8(v);
                }
            }
        }
    } else {
        const int segEnd = offs[e] + meta[e * 16];   // valid slots < segEnd
        const float se = slope[e];
        float psum = 0.f;
#pragma unroll
        for (int ni = 0; ni < 2; ++ni) {
            int col = n0 + wn * 64 + ni * 32 + l31;
            float bv  = bias[e * 1024 + col];
            float w3s = W3[e * 1024 + col] * se;
#pragma unroll
            for (int mi = 0; mi < 4; ++mi) {
                int rowb = m0 + wm * 128 + mi * 32 + 4 * khalf;
#pragma unroll
                for (int reg = 0; reg < 16; ++reg) {
                    int rowg = rowb + (reg & 3) + 8 * (reg >> 2);
                    float v = acc[mi][ni][reg] + bv;
                    v = v > 0.f ? v : 0.f;
                    psum += (rowg < segEnd) ? v * w3s : 0.f;
                }
            }
        }
#pragma unroll
        for (int o = 32; o; o >>= 1) psum += __shfl_xor(psum, o, 64);
        float* red = (float*)As;    // safe: all LDS reads done (loop-final barrier)
        if (lane == 0) red[w] = psum;
        __syncthreads();
        if (t == 0) atomicAdd(out, red[0] + red[1] + red[2] + red[3]);
    }
}

extern "C" void kernel_launch(void* const* d_in, const int* in_sizes, int n_in,
                              void* d_out, int out_size, void* d_ws, size_t ws_size,
                              hipStream_t stream) {
    const float* features = (const float*)d_in[0];
    const int*   sym      = (const int*)d_in[1];
    const float* W1       = (const float*)d_in[2];
    const float* b1       = (const float*)d_in[3];
    const float* W2       = (const float*)d_in[4];
    const float* b2       = (const float*)d_in[5];
    const float* W3       = (const float*)d_in[6];
    const float* b3       = (const float*)d_in[7];
    const float* slope    = (const float*)d_in[8];
    const float* inter    = (const float*)d_in[9];
    float* out = (float*)d_out;

    char* ws  = (char*)d_ws;
    u8*  Xp   = (u8*)(ws + XP_OFF);
    u8*  H1b  = (u8*)(ws + H1_OFF);
    u8*  W1T  = (u8*)(ws + W1T_OFF);
    u8*  W2T  = (u8*)(ws + W2T_OFF);
    int* perm = (int*)(ws + PERM_OFF);
    int* meta = (int*)(ws + META_OFF);

    k_count<<<NATOMS / 256, 256, 0, stream>>>(sym, meta);
    k_offsets<<<1, 256, 0, stream>>>(meta, slope, b3, inter, out);
    k_scatter<<<NATOMS / 256, 256, 0, stream>>>(sym, meta, perm);
    k_convx<<<(MCAP * 128) / 256, 256, 0, stream>>>(features, perm, meta, Xp);
    k_transw<<<dim3(256, 4, 2), 256, 0, stream>>>(W1, W1T, W2, W2T);
    k_gemm<false><<<dim3(8, 132), 256, 0, stream>>>(Xp, W1T, b1, H1b, meta,
                                                    nullptr, nullptr, nullptr);
    k_gemm<true><<<dim3(8, 132), 256, 0, stream>>>(H1b, W2T, b2, nullptr, meta,
                                                   W3, slope, out);
}

// Round 4
// 339.086 us; speedup vs baseline: 2.1351x; 1.0245x over previous
//
#include <hip/hip_runtime.h>
#include <hip/hip_bf16.h>
#include <stdint.h>

// Problem constants
#define NATOMS 32768
#define DDIM   1024
#define HDIM   1024
#define ENUM   4
// Expert segments padded to 256 so a 256-row GEMM tile never spans two experts.
// Worst-case padded M <= 33536; cap 33792 (132*256) for slack.
#define MCAP   33792

typedef unsigned short u16;
typedef unsigned char  u8;
typedef __attribute__((ext_vector_type(8)))  int   i32x8;
typedef __attribute__((ext_vector_type(16))) float f32x16;

// ---- workspace layout (bytes) ----
static const size_t XP_OFF   = 0;
static const size_t H1_OFF   = XP_OFF  + (size_t)MCAP * 1024;
static const size_t W1T_OFF  = H1_OFF  + (size_t)MCAP * 1024;
static const size_t W2T_OFF  = W1T_OFF + (size_t)ENUM * 1024 * 1024;
static const size_t PERM_OFF = W2T_OFF + (size_t)ENUM * 1024 * 1024;
static const size_t META_OFF = PERM_OFF + (size_t)MCAP * 4;
// meta ints: count[e] at e*16; cursor[e] at 64+e*16; offs[0..3] at 128..131;
// Mpad at 132; per-block count partials at 256 + b*4 + e  (b in [0,128))

__device__ __forceinline__ u8 f2fp8(float x) {
    int w = __builtin_amdgcn_cvt_pk_fp8_f32(x, x, 0, false);
    return (u8)(w & 0xFF);
}

// ------- count atoms per expert: per-block partials, no pre-zeroed meta -------
__global__ void k_count(const int* __restrict__ sym, int* __restrict__ meta) {
    __shared__ int cnt[4];
    int t = threadIdx.x;
    if (t < 4) cnt[t] = 0;
    __syncthreads();
    int n = blockIdx.x * 256 + t;
    int lane = t & 63;
    int e = sym[n];
#pragma unroll
    for (int j = 0; j < ENUM; ++j) {
        unsigned long long mask = __ballot(e == j);
        if (mask) {
            int leader = __ffsll((long long)mask) - 1;
            if (lane == leader) atomicAdd(&cnt[j], __popcll(mask));
        }
    }
    __syncthreads();
    if (t < 4) meta[256 + blockIdx.x * 4 + t] = cnt[t];
}

// -- sum partials; write counts/cursors/offs/Mpad; init pad perm slots to 0;
// -- out = constant energy term --
__global__ void k_offsets(int* __restrict__ meta, const float* __restrict__ slope,
                          const float* __restrict__ b3, const float* __restrict__ inter,
                          float* __restrict__ out, int* __restrict__ perm) {
    __shared__ int tot[4], padS[4], padE[4];
    int t = threadIdx.x;
    if (t < 4) {
        int s = 0;
#pragma unroll 8
        for (int b = 0; b < 128; ++b) s += meta[256 + b * 4 + t];
        tot[t] = s;
    }
    __syncthreads();
    if (t == 0) {
        int off = 0;
        float c = 0.f;
        for (int e = 0; e < 4; ++e) {
            int cnt = tot[e];
            meta[e * 16]     = cnt;   // total count
            meta[128 + e]    = off;   // segment start
            meta[64 + e*16]  = off;   // scatter cursor
            padS[e] = off + cnt;      // pad range [padS, padE)
            c += (float)cnt * (slope[e] * b3[e] + inter[e]);
            off += (cnt + 255) & ~255;   // pad to 256 for 256-row tiles
            padE[e] = off;
        }
        meta[132] = off;              // Mpad
        out[0] = c;                   // per-atom constant terms, summed
    }
    __syncthreads();
    // R12: pad perm slots -> row 0, so gemm1's permuted staging reads valid
    // memory (pad rows produce garbage h1, masked by segEnd in FUSE epilogue).
#pragma unroll
    for (int e = 0; e < 4; ++e)
        for (int i = padS[e] + t; i < padE[e]; i += 256) perm[i] = 0;
}

// ---------------- scatter atom ids (wave-aggregated: 4 atomics/wave) ----------------
__global__ void k_scatter(const int* __restrict__ sym, int* __restrict__ meta,
                          int* __restrict__ perm) {
    int n = blockIdx.x * 256 + threadIdx.x;
    int lane = threadIdx.x & 63;
    int e = sym[n];
#pragma unroll
    for (int j = 0; j < ENUM; ++j) {
        unsigned long long mask = __ballot(e == j);
        if (mask) {
            int leader = __ffsll((long long)mask) - 1;
            int base = 0;
            if (lane == leader)
                base = atomicAdd(&meta[64 + j * 16], __popcll(mask));
            base = __shfl(base, leader, 64);
            if (e == j) {
                int rank = __popcll(mask & ((1ull << lane) - 1ull));
                perm[base + rank] = n;
            }
        }
    }
}

// -------- features fp32 -> fp8, STREAMING (R12: no perm gather; permutation
// -------- moved into gemm1's per-lane global_load_lds source addresses) --------
__global__ void k_conv8(const float* __restrict__ F, u8* __restrict__ X8) {
    int g = blockIdx.x * 256 + threadIdx.x;    // chunk of 8 elements
    const float* fp = F + (size_t)g * 8;
    int w0 = 0, w1 = 0;
    w0 = __builtin_amdgcn_cvt_pk_fp8_f32(fp[0], fp[1], w0, false);
    w0 = __builtin_amdgcn_cvt_pk_fp8_f32(fp[2], fp[3], w0, true);
    w1 = __builtin_amdgcn_cvt_pk_fp8_f32(fp[4], fp[5], w1, false);
    w1 = __builtin_amdgcn_cvt_pk_fp8_f32(fp[6], fp[7], w1, true);
    uint2 v; v.x = (unsigned)w0; v.y = (unsigned)w1;
    *(uint2*)(void*)(X8 + (size_t)g * 8) = v;
}

// -------- W [E][K][N] fp32 -> WT [E][N][K] fp8 of 32*W (z: 0=W1,1=W2) --------
__global__ void k_transw(const float* __restrict__ W1, u8* __restrict__ W1T,
                         const float* __restrict__ W2, u8* __restrict__ W2T) {
    __shared__ u8 tile[64][65];
    const float* W  = blockIdx.z ? W2  : W1;
    u8*          WT = blockIdx.z ? W2T : W1T;
    int e  = blockIdx.y;
    int tn = blockIdx.x & 15;
    int tk = blockIdx.x >> 4;
    const float* Wp = W  + (size_t)e * 1024 * 1024;
    u8*         WTp = WT + (size_t)e * 1024 * 1024;
    int c = threadIdx.x & 63, r0 = threadIdx.x >> 6;
#pragma unroll
    for (int i = 0; i < 16; ++i) {
        int r = r0 + i * 4;
        tile[r][c] = f2fp8(32.0f * Wp[(size_t)(tk * 64 + r) * 1024 + tn * 64 + c]);
    }
    __syncthreads();
#pragma unroll
    for (int i = 0; i < 16; ++i) {
        int r = r0 + i * 4;
        WTp[(size_t)(tn * 64 + r) * 1024 + tk * 64 + c] = tile[c][r];
    }
}

// ---------------- MX-fp8 MFMA GEMM: relu(A * (32B)^T * 2^-5 + bias) ----------------
// R12 = R11 skeleton (single-buffered LDS, __syncthreads 2-barrier K-loop,
// 256x128 tile, 4 waves of 128x64, 2 blocks/CU) with two fixes:
// (1) FULL bank-conflict-free LDS swizzle: chunk c of row r holds global chunk
//     c ^ (r&7) ^ ((r>>3)&3). R7/R11's c^(r&7) left a 4-way conflict: the 4
//     lanes of l31 with equal (row&7) (rows x,x+8,x+16,x+24) hit the same
//     4-bank group (R10 PMC: SQ_LDS_BANK_CONFLICT 3.19M/gemm). The extra
//     ((r>>3)&3) term spreads them; involution holds on both sides.
// (2) PERM template arg: gemm1 stages A rows via per-lane PERMUTED global
//     source addresses (perm[m0+row]*1024) -- global_load_lds's global source
//     is per-lane (m173); only its LDS dest must be linear. This moved the
//     permutation out of the conversion kernel (now pure streaming).
// XCD swizzle: grid dim3(8,132) -> 1056 = 132*8 chunked bijective; nt fastest
// per XCD so the 8 blocks sharing an A-panel are co-XCD.
// FUSE=false: store fp8 C.  FUSE=true: fold layer3 dot + slope + global sum.
template <bool FUSE, bool PERM>
__global__ __launch_bounds__(256, 2)
void k_gemm(const u8* __restrict__ A, const u8* __restrict__ BT,
            const float* __restrict__ bias, u8* __restrict__ C,
            const int* __restrict__ meta, const float* __restrict__ W3,
            const float* __restrict__ slope, float* __restrict__ out,
            const int* __restrict__ perm) {
    __shared__ u8 As[256 * 128];   // 32 KB
    __shared__ u8 Bs[128 * 128];   // 16 KB
    const int* offs = meta + 128;

    // grid = dim3(8, 132) -> flat 0..1055; XCD = flat&7 gets contiguous chunk
    const int flat = blockIdx.y * 8 + blockIdx.x;
    const int wgid = (flat & 7) * 132 + (flat >> 3);
    const int mt = wgid >> 3;                  // m tile (0..131), 256 rows
    const int nt = wgid & 7;                   // n tile (0..7), fast index
    const int m0 = mt * 256, n0 = nt * 128;
    if (m0 >= meta[132]) return;               // beyond actual padded M
    const int e = (m0 >= offs[1]) + (m0 >= offs[2]) + (m0 >= offs[3]);

    const int t = threadIdx.x;                 // 0..255
    const int w = t >> 6, lane = t & 63;
    const int l31 = lane & 31, khalf = lane >> 5;
    const int wm = w & 1, wn = w >> 1;         // 2x2 waves, each 128x64

    const u8* Bg = BT + (size_t)e * 1024 * 1024 + (size_t)n0 * 1024;

    // staging: instr i covers rows i*32+(t>>3), 16B chunk t&7; source chunk
    // pre-swizzled (t&7)^(r&7)^((r>>3)&3); LDS linear (global_load_lds rule).
    const int srow = t >> 3;                   // 0..31
    const int gcol = (((t & 7) ^ (srow & 7) ^ ((srow >> 3) & 3)) * 16);

    // per-lane row base pointers (PERM: indirect through perm[], pads -> row 0)
    const u8* arow[8];
#pragma unroll
    for (int i = 0; i < 8; ++i) {
        int r = i * 32 + srow;
        size_t src = PERM ? (size_t)perm[m0 + r] : (size_t)(m0 + r);
        arow[i] = A + src * 1024 + gcol;
    }
    const u8* brow[4];
#pragma unroll
    for (int i = 0; i < 4; ++i)
        brow[i] = Bg + (size_t)(i * 32 + srow) * 1024 + gcol;

    f32x16 acc[4][2] = {};

    for (int kt = 0; kt < 1024 / 128; ++kt) {
        const int kb = kt * 128;
#pragma unroll
        for (int i = 0; i < 8; ++i)            // A: 256 rows, 8 instrs
            __builtin_amdgcn_global_load_lds((const void*)(arow[i] + kb),
                (void*)(As + i * 4096 + w * 1024), 16, 0, 0);
#pragma unroll
        for (int i = 0; i < 4; ++i)            // B: 128 rows, 4 instrs
            __builtin_amdgcn_global_load_lds((const void*)(brow[i] + kb),
                (void*)(Bs + i * 4096 + w * 1024), 16, 0, 0);
        __syncthreads();

#pragma unroll
        for (int kk = 0; kk < 2; ++kk) {
            const int c0 = 4 * kk + 2 * khalf;    // even
            i32x8 b[2];
#pragma unroll
            for (int ni = 0; ni < 2; ++ni) {
                int n = wn * 64 + ni * 32 + l31;
                const u8* base = Bs + n * 128;
                int sw = (n & 7) ^ ((n >> 3) & 3);
                int lo = ((c0 ^ sw) << 4);
                union { uint4 q[2]; i32x8 v; } u;
                u.q[0] = *(const uint4*)(const void*)(base + lo);
                u.q[1] = *(const uint4*)(const void*)(base + (lo ^ 16));
                b[ni] = u.v;
            }
#pragma unroll
            for (int mi = 0; mi < 4; ++mi) {
                int m = wm * 128 + mi * 32 + l31;
                const u8* base = As + m * 128;
                int sw = (m & 7) ^ ((m >> 3) & 3);
                int lo = ((c0 ^ sw) << 4);
                union { uint4 q[2]; i32x8 v; } u;
                u.q[0] = *(const uint4*)(const void*)(base + lo);
                u.q[1] = *(const uint4*)(const void*)(base + (lo ^ 16));
                i32x8 a = u.v;
#pragma unroll
                for (int ni = 0; ni < 2; ++ni)
                    acc[mi][ni] = __builtin_amdgcn_mfma_scale_f32_32x32x64_f8f6f4(
                        a, b[ni], acc[mi][ni],
                        0, 0,                       // cbsz=fp8(e4m3), blgp=fp8(e4m3)
                        0, 0x7F7F7F7F,              // A scale 2^0
                        0, 0x7A7A7A7A);             // B scale 2^-5 (undo 32*W)
            }
        }
        __syncthreads();
    }

    // epilogue.  32x32 C/D layout: col=lane&31, row=(reg&3)+8*(reg>>2)+4*(lane>>5)
    if (!FUSE) {
#pragma unroll
        for (int ni = 0; ni < 2; ++ni) {
            int col = n0 + wn * 64 + ni * 32 + l31;
            float bv = bias[e * 1024 + col];
#pragma unroll
            for (int mi = 0; mi < 4; ++mi) {
                int rowb = m0 + wm * 128 + mi * 32 + 4 * khalf;
#pragma unroll
                for (int reg = 0; reg < 16; ++reg) {
                    int rowg = rowb + (reg & 3) + 8 * (reg >> 2);
                    float v = acc[mi][ni][reg] + bv;
                    v = v > 0.f ? v : 0.f;
                    C[(size_t)rowg * 1024 + col] = f2fp8(v);
                }
            }
        }
    } else {
        const int segEnd = offs[e] + meta[e * 16];   // valid slots < segEnd
        const float se = slope[e];
        float psum = 0.f;
#pragma unroll
        for (int ni = 0; ni < 2; ++ni) {
            int col = n0 + wn * 64 + ni * 32 + l31;
            float bv  = bias[e * 1024 + col];
            float w3s = W3[e * 1024 + col] * se;
#pragma unroll
            for (int mi = 0; mi < 4; ++mi) {
                int rowb = m0 + wm * 128 + mi * 32 + 4 * khalf;
#pragma unroll
                for (int reg = 0; reg < 16; ++reg) {
                    int rowg = rowb + (reg & 3) + 8 * (reg >> 2);
                    float v = acc[mi][ni][reg] + bv;
                    v = v > 0.f ? v : 0.f;
                    psum += (rowg < segEnd) ? v * w3s : 0.f;
                }
            }
        }
#pragma unroll
        for (int o = 32; o; o >>= 1) psum += __shfl_xor(psum, o, 64);
        float* red = (float*)As;    // safe: all LDS reads done (loop-final barrier)
        if (lane == 0) red[w] = psum;
        __syncthreads();
        if (t == 0) atomicAdd(out, red[0] + red[1] + red[2] + red[3]);
    }
}

extern "C" void kernel_launch(void* const* d_in, const int* in_sizes, int n_in,
                              void* d_out, int out_size, void* d_ws, size_t ws_size,
                              hipStream_t stream) {
    const float* features = (const float*)d_in[0];
    const int*   sym      = (const int*)d_in[1];
    const float* W1       = (const float*)d_in[2];
    const float* b1       = (const float*)d_in[3];
    const float* W2       = (const float*)d_in[4];
    const float* b2       = (const float*)d_in[5];
    const float* W3       = (const float*)d_in[6];
    const float* b3       = (const float*)d_in[7];
    const float* slope    = (const float*)d_in[8];
    const float* inter    = (const float*)d_in[9];
    float* out = (float*)d_out;

    char* ws  = (char*)d_ws;
    u8*  X8   = (u8*)(ws + XP_OFF);
    u8*  H1b  = (u8*)(ws + H1_OFF);
    u8*  W1T  = (u8*)(ws + W1T_OFF);
    u8*  W2T  = (u8*)(ws + W2T_OFF);
    int* perm = (int*)(ws + PERM_OFF);
    int* meta = (int*)(ws + META_OFF);

    k_count<<<NATOMS / 256, 256, 0, stream>>>(sym, meta);
    k_offsets<<<1, 256, 0, stream>>>(meta, slope, b3, inter, out, perm);
    k_scatter<<<NATOMS / 256, 256, 0, stream>>>(sym, meta, perm);
    k_conv8<<<(NATOMS * 128) / 256, 256, 0, stream>>>(features, X8);
    k_transw<<<dim3(256, 4, 2), 256, 0, stream>>>(W1, W1T, W2, W2T);
    k_gemm<false, true><<<dim3(8, 132), 256, 0, stream>>>(X8, W1T, b1, H1b, meta,
                                                          nullptr, nullptr, nullptr,
                                                          perm);
    k_gemm<true, false><<<dim3(8, 132), 256, 0, stream>>>(H1b, W2T, b2, nullptr,
                                                          meta, W3, slope, out,
                                                          nullptr);
}